// Round 13
// baseline (99.119 us; speedup 1.0000x reference)
//
#include <hip/hip_runtime.h>
#include <hip/hip_bf16.h>
#include <math.h>

// Q=4096, N=50000, D=5, L=2
// t[q][n] = 2g*(x.r) - g|x|^2 - g|r|^2, g = log2e/(2 sigma^2);  s = 2^t
// K=8 augmented dot on the MFMA pipe, split-bf16 (hi+lo) packed into K=32:
//   A32 = [Ah|Ah|Al|0], B32 = [Bh|Bl|Bh|0] => Ah.Bh + Ah.Bl + Al.Bh
// R13 = R10-verbatim (proven absmax 1.22e-4) + __launch_bounds__(256,3):
// ~170-VGPR budget so frags+accumulators+MFMA C/D stay in arch VGPRs
// (at (256,4)/56 VGPR the compiler split accumulators into AGPRs, paying
// v_accvgpr round-trips per update — suspected ~30% of per-iter VALU issue).
#define QTOT   4096
#define NTOT   50000
#define NTILES 3125            // 50000/16
#define NS     64              // n-phases; wave phase = nb*4 + waveid
#define NB     16              // n-blocks per q-group
#define QG     64              // q-groups (64 queries each)
#define MAINBLOCKS (QG * NB)   // 1024 blocks = 4096 waves
#define LSTEP  (NS * 16 * 8)   // Loc stream stride per iteration (bytes)

// ws layout (bytes) — identical to the R7/R10 layout that passed
#define BOFF   0u                          // B: [ntile][2][16][8 bf16] = 512 B/tile
#define BSIZE  (3125u * 512u)              // 1,600,000
#define AOFF   (BOFF + BSIZE)              // A: [q][2][8 bf16] = 32 B/q
#define ASIZE  (4096u * 32u)               // 131,072
#define ZOFF   (AOFF + ASIZE)              // 256 B zero block
#define PARTOFF (ZOFF + 256u)              // part: [NB][3][4096] f32 = 786,432 B

typedef unsigned short ushort_t;
typedef short  s16x8 __attribute__((ext_vector_type(8)));
typedef float  f32x4 __attribute__((ext_vector_type(4)));
typedef float  f2    __attribute__((ext_vector_type(2)));

#if __has_builtin(__builtin_amdgcn_exp2f)
#define EXP2F(x) __builtin_amdgcn_exp2f(x)
#else
#define EXP2F(x) exp2f(x)
#endif

static __device__ __forceinline__ f2 fma2(f2 a, f2 b, f2 c) {
#if __has_builtin(__builtin_elementwise_fma)
    return __builtin_elementwise_fma(a, b, c);
#else
    f2 r; r.x = fmaf(a.x, b.x, c.x); r.y = fmaf(a.y, b.y, c.y); return r;
#endif
}

static __device__ __forceinline__ void bsplit(float f, ushort_t& h, ushort_t& l) {
    __hip_bfloat16 hb = __float2bfloat16(f);
    float hf = __bfloat162float(hb);
    __hip_bfloat16 lb = __float2bfloat16(f - hf);
    h = *reinterpret_cast<ushort_t*>(&hb);
    l = *reinterpret_cast<ushort_t*>(&lb);
}

__global__ __launch_bounds__(256) void sknn_prep(
    const float* __restrict__ rss, const float* __restrict__ Radio,
    const float* __restrict__ sigma, char* __restrict__ ws)
{
    const int p = blockIdx.x * 256 + threadIdx.x;
    const float sg = sigma[0];
    const float g  = 1.4426950408889634f / (2.0f * sg * sg);
    const float g2 = 2.0f * g;

    if (p < NTOT) {
        float b[8]; float rr = 0.f;
        #pragma unroll
        for (int d = 0; d < 5; ++d) { float r = Radio[p*5+d]; b[d] = g2*r; rr += r*r; }
        b[5] = 1.0f; b[6] = -g * rr; b[7] = 0.0f;
        union { ushort_t u[8]; f32x4 v; } hi, lo;
        #pragma unroll
        for (int k = 0; k < 8; ++k) bsplit(b[k], hi.u[k], lo.u[k]);
        const int nt = p >> 4, nsub = p & 15;
        *(f32x4*)(ws + BOFF + (unsigned)nt*512u + (unsigned)nsub*16u)        = hi.v;
        *(f32x4*)(ws + BOFF + (unsigned)nt*512u + 256u + (unsigned)nsub*16u) = lo.v;
    }
    if (p < QTOT) {
        float a[8]; float xx = 0.f;
        #pragma unroll
        for (int d = 0; d < 5; ++d) { float x = rss[p*5+d]; a[d] = x; xx += x*x; }
        a[5] = -g * xx; a[6] = 1.0f; a[7] = 0.0f;
        union { ushort_t u[8]; f32x4 v; } hi, lo;
        #pragma unroll
        for (int k = 0; k < 8; ++k) bsplit(a[k], hi.u[k], lo.u[k]);
        *(f32x4*)(ws + AOFF + (unsigned)p*32u)       = hi.v;
        *(f32x4*)(ws + AOFF + (unsigned)p*32u + 16u) = lo.v;
    }
    if (p < 16) *(f32x4*)(ws + ZOFF + (unsigned)p*16u) = (f32x4){0.f,0.f,0.f,0.f};
}

// Main: block = (qg, nb); 4 waves share the q-group, phases ns = nb*4+w.
// nb = blockIdx & 15 -> XCD (blockIdx%8) only streams 8 of 64 phases
// (~250 KB of B+Loc per XCD L2, resident).
// Per n-tile: 1x 16B/lane B load, 4 MFMA, 16 exp2, fp32 accum.
// K-loop peeled: 48 hot iters with unconditional prefetch + final iter.
// C/D: col = lane&15 (n), row = (lane>>4)*4 + reg (q).
__global__ __launch_bounds__(256, 3) void sknn_main(
    const char* __restrict__ tbl, const float* __restrict__ Loc,
    float* __restrict__ part)
{
    const int tid  = threadIdx.x;
    const int lane = tid & 63;
    const int w    = tid >> 6;                        // wave in block: 0..3
    const int nb   = blockIdx.x & (NB - 1);           // 0..15 (XCD swizzle)
    const int qg   = blockIdx.x >> 4;                 // 0..63
    const int ns   = nb * 4 + w;                      // phase 0..63
    const int qbase = qg * 64;
    const int j  = lane & 15;
    const int qd = lane >> 4;

    // A frags: quadrants 0,1 -> Ah; 2 -> Al; 3 -> zeros
    const unsigned abase = (qd == 3) ? (ZOFF + (unsigned)j*16u)
        : (AOFF + (unsigned)(qbase + j)*32u + (qd == 2 ? 16u : 0u));
    const unsigned astep = (qd == 3) ? 0u : 512u;
    const s16x8 a0 = *(const s16x8*)(tbl + abase);
    const s16x8 a1 = *(const s16x8*)(tbl + abase + astep);
    const s16x8 a2 = *(const s16x8*)(tbl + abase + 2u*astep);
    const s16x8 a3 = *(const s16x8*)(tbl + abase + 3u*astep);

    // B stream: quadrants 0->Bh, 1->Bl, 2->Bh, 3->0
    unsigned bofs = (qd == 3) ? (ZOFF + (unsigned)j*16u)
        : (BOFF + (unsigned)ns*512u + (qd == 1 ? 256u : 0u) + (unsigned)j*16u);
    const unsigned bstep = (qd == 3) ? 0u : (512u * NS);

    unsigned lofs = (unsigned)(ns*16 + j) * 8u;       // lane's col-n Loc (8B)
    const char* locb = (const char*)Loc;

    f2 sm2[8]; f2 o[16];
    #pragma unroll
    for (int k = 0; k < 8;  ++k) sm2[k] = (f2){0.f, 0.f};
    #pragma unroll
    for (int k = 0; k < 16; ++k) o[k]   = (f2){0.f, 0.f};
    const f32x4 zz = {0.f, 0.f, 0.f, 0.f};

    s16x8 bcur = *(const s16x8*)(tbl + bofs);
    f2    lcur = *(const f2*)(locb + lofs);

    int nt = ns;
    // hot loop: guaranteed next tile -> unconditional prefetch, no guards
    while (nt + NS < NTILES) {
        bofs += bstep;
        lofs += (unsigned)LSTEP;
        const s16x8 bnx = *(const s16x8*)(tbl + bofs);
        const f2    lnx = *(const f2*)(locb + lofs);

        f32x4 t[4];
        t[0] = __builtin_amdgcn_mfma_f32_16x16x32_bf16(a0, bcur, zz, 0, 0, 0);
        t[1] = __builtin_amdgcn_mfma_f32_16x16x32_bf16(a1, bcur, zz, 0, 0, 0);
        t[2] = __builtin_amdgcn_mfma_f32_16x16x32_bf16(a2, bcur, zz, 0, 0, 0);
        t[3] = __builtin_amdgcn_mfma_f32_16x16x32_bf16(a3, bcur, zz, 0, 0, 0);

        #pragma unroll
        for (int qt = 0; qt < 4; ++qt) {
            const float s0 = EXP2F(t[qt][0]);
            const float s1 = EXP2F(t[qt][1]);
            const float s2 = EXP2F(t[qt][2]);
            const float s3 = EXP2F(t[qt][3]);
            sm2[qt*2+0] += (f2){s0, s1};
            sm2[qt*2+1] += (f2){s2, s3};
            o[qt*4+0] = fma2((f2){s0, s0}, lcur, o[qt*4+0]);
            o[qt*4+1] = fma2((f2){s1, s1}, lcur, o[qt*4+1]);
            o[qt*4+2] = fma2((f2){s2, s2}, lcur, o[qt*4+2]);
            o[qt*4+3] = fma2((f2){s3, s3}, lcur, o[qt*4+3]);
        }
        bcur = bnx; lcur = lnx;
        nt += NS;
    }
    // final tile (no prefetch)
    {
        f32x4 t[4];
        t[0] = __builtin_amdgcn_mfma_f32_16x16x32_bf16(a0, bcur, zz, 0, 0, 0);
        t[1] = __builtin_amdgcn_mfma_f32_16x16x32_bf16(a1, bcur, zz, 0, 0, 0);
        t[2] = __builtin_amdgcn_mfma_f32_16x16x32_bf16(a2, bcur, zz, 0, 0, 0);
        t[3] = __builtin_amdgcn_mfma_f32_16x16x32_bf16(a3, bcur, zz, 0, 0, 0);

        #pragma unroll
        for (int qt = 0; qt < 4; ++qt) {
            const float s0 = EXP2F(t[qt][0]);
            const float s1 = EXP2F(t[qt][1]);
            const float s2 = EXP2F(t[qt][2]);
            const float s3 = EXP2F(t[qt][3]);
            sm2[qt*2+0] += (f2){s0, s1};
            sm2[qt*2+1] += (f2){s2, s3};
            o[qt*4+0] = fma2((f2){s0, s0}, lcur, o[qt*4+0]);
            o[qt*4+1] = fma2((f2){s1, s1}, lcur, o[qt*4+1]);
            o[qt*4+2] = fma2((f2){s2, s2}, lcur, o[qt*4+2]);
            o[qt*4+3] = fma2((f2){s3, s3}, lcur, o[qt*4+3]);
        }
    }

    // In-wave butterfly over each 16-lane column group
    #pragma unroll
    for (int m = 1; m <= 8; m <<= 1) {
        #pragma unroll
        for (int k = 0; k < 8; ++k) {
            sm2[k].x += __shfl_xor(sm2[k].x, m, 64);
            sm2[k].y += __shfl_xor(sm2[k].y, m, 64);
        }
        #pragma unroll
        for (int k = 0; k < 16; ++k) {
            o[k].x += __shfl_xor(o[k].x, m, 64);
            o[k].y += __shfl_xor(o[k].y, m, 64);
        }
    }

    // Cross-wave reduction in LDS: red[wave][comp][q_local]
    __shared__ float red[4][3][64];
    #pragma unroll
    for (int qt = 0; qt < 4; ++qt) {
        #pragma unroll
        for (int i = 0; i < 4; ++i) {
            if (j == qt*4 + i) {
                const int ql = qt*16 + qd*4 + i;
                red[w][0][ql] = (i & 1) ? sm2[qt*2 + (i>>1)].y
                                        : sm2[qt*2 + (i>>1)].x;
                red[w][1][ql] = o[qt*4+i].x;
                red[w][2][ql] = o[qt*4+i].y;
            }
        }
    }
    __syncthreads();

    // 192 threads: sum 4 waves, one plain coalesced store each (no atomics).
    if (tid < 192) {
        const int comp = tid >> 6, ql = tid & 63;
        const float v = red[0][comp][ql] + red[1][comp][ql]
                      + red[2][comp][ql] + red[3][comp][ql];
        part[((nb * 3 + comp) << 12) + qbase + ql] = v;
    }
}

__global__ __launch_bounds__(256) void sknn_fin(
    const float* __restrict__ part, float* __restrict__ out)
{
    const int q = blockIdx.x * 256 + threadIdx.x;   // 16 blocks cover 4096
    float s = 0.f, w0 = 0.f, w1 = 0.f;
    #pragma unroll
    for (int nb = 0; nb < NB; ++nb) {
        s  += part[((nb * 3 + 0) << 12) + q];
        w0 += part[((nb * 3 + 1) << 12) + q];
        w1 += part[((nb * 3 + 2) << 12) + q];
    }
    const float inv = 1.0f / s;
    out[q * 2 + 0] = w0 * inv;
    out[q * 2 + 1] = w1 * inv;
}

extern "C" void kernel_launch(void* const* d_in, const int* in_sizes, int n_in,
                              void* d_out, int out_size, void* d_ws, size_t ws_size,
                              hipStream_t stream) {
    const float* rss   = (const float*)d_in[0];
    const float* Radio = (const float*)d_in[1];
    const float* Loc   = (const float*)d_in[2];
    const float* sigma = (const float*)d_in[3];
    float* out  = (float*)d_out;
    char*  ws   = (char*)d_ws;
    float* part = (float*)(ws + PARTOFF);

    sknn_prep<<<(NTOT + 255) / 256, dim3(256), 0, stream>>>(rss, Radio, sigma, ws);
    sknn_main<<<MAINBLOCKS, dim3(256), 0, stream>>>(ws, Loc, part);
    sknn_fin<<<QTOT / 256, dim3(256), 0, stream>>>(part, out);
}

// Round 14
// 96.708 us; speedup vs baseline: 1.0249x; 1.0249x over previous
//
#include <hip/hip_runtime.h>
#include <hip/hip_bf16.h>
#include <math.h>

// Q=4096, N=50000, D=5, L=2
// GEMM1 (16x16x32, split-bf16 K-packing, A=refs, B=queries):
//   t[ref][q] tile; C/D: col=lane&15=q, row=4*quad+reg=ref
// s = 2^t -> bf16 -> fed DIRECTLY as B-frag of GEMM2 (16x16x16, n=lane&15=q,
//   k=4*quad+i=ref — identical lane mapping, no shuffle/transpose).
// GEMM2 A rows: {l0_hi, l0_lo, l1_hi, l1_lo, 1, 0...} (split-bf16 Loc) ->
//   C2 rows accumulate {o0h,o0l,o1h,o1l,sum} over the whole sweep in AGPRs.
#define QTOT   4096
#define NTOT   50000
#define NTILES 3125            // 50000/16 exactly
#define NS     64              // n-phases; wave phase = nb*4 + waveid
#define NB     16
#define QG     64
#define MAINBLOCKS (QG * NB)   // 1024 blocks = 4096 waves
#define ASTEP_IT  (512u * NS)  // ref-table stride per iter
#define LTSTEP_IT (160u * NS)  // loc-table stride per iter
#define PREPN  (NTILES * 20)   // 62500 compact loc-table entries

// ws layout (bytes); total 3,017,760 (< R12's proven-OK 2.97 MB)
#define BOFF   0u                          // ref table: [tile][hi16x16B][lo16x16B]
#define BSIZE  (3125u * 512u)              // 1,600,000
#define AOFF   (BOFF + BSIZE)              // query table: [q][hi16B][lo16B]
#define ASIZE  (4096u * 32u)               // 131,072
#define ZOFF   (AOFF + ASIZE)              // 256 B zero block
#define LTOFF  (ZOFF + 256u)               // loc table: [tile][20 entries][8B]
#define LTSIZE (3125u * 160u)              // 500,000
#define PARTOFF (LTOFF + LTSIZE)           // part: [NB][3][4096] f32

typedef unsigned short ushort_t;
typedef short  s16x8 __attribute__((ext_vector_type(8)));
typedef short  s16x4 __attribute__((ext_vector_type(4)));
typedef float  f32x4 __attribute__((ext_vector_type(4)));

#if __has_builtin(__builtin_amdgcn_exp2f)
#define EXP2F(x) __builtin_amdgcn_exp2f(x)
#else
#define EXP2F(x) exp2f(x)
#endif

#if __has_builtin(__builtin_amdgcn_mfma_f32_16x16x16_bf16)
#define MFMA16(a,b,c) __builtin_amdgcn_mfma_f32_16x16x16_bf16(a,b,c,0,0,0)
#else
#define MFMA16(a,b,c) __builtin_amdgcn_mfma_f32_16x16x16bf16_1k(a,b,c,0,0,0)
#endif

static __device__ __forceinline__ void bsplit(float f, ushort_t& h, ushort_t& l) {
    __hip_bfloat16 hb = __float2bfloat16(f);
    float hf = __bfloat162float(hb);
    __hip_bfloat16 lb = __float2bfloat16(f - hf);
    h = *reinterpret_cast<ushort_t*>(&hb);
    l = *reinterpret_cast<ushort_t*>(&lb);
}

static __device__ __forceinline__ ushort_t b16(float f) {
    __hip_bfloat16 hb = __float2bfloat16(f);
    return *reinterpret_cast<ushort_t*>(&hb);
}

__global__ __launch_bounds__(256) void sknn_prep(
    const float* __restrict__ rss, const float* __restrict__ Radio,
    const float* __restrict__ Loc, const float* __restrict__ sigma,
    char* __restrict__ ws)
{
    const int p = blockIdx.x * 256 + threadIdx.x;   // grid covers PREPN
    const float sg = sigma[0];
    const float g  = 1.4426950408889634f / (2.0f * sg * sg);
    const float g2 = 2.0f * g;

    if (p < NTOT) {    // ref entry (unchanged from R10): {2g*r, 1, -g|r|^2, 0}
        float b[8]; float rr = 0.f;
        #pragma unroll
        for (int d = 0; d < 5; ++d) { float r = Radio[p*5+d]; b[d] = g2*r; rr += r*r; }
        b[5] = 1.0f; b[6] = -g * rr; b[7] = 0.0f;
        union { ushort_t u[8]; f32x4 v; } hi, lo;
        #pragma unroll
        for (int k = 0; k < 8; ++k) bsplit(b[k], hi.u[k], lo.u[k]);
        const int nt = p >> 4, nsub = p & 15;
        *(f32x4*)(ws + BOFF + (unsigned)nt*512u + (unsigned)nsub*16u)        = hi.v;
        *(f32x4*)(ws + BOFF + (unsigned)nt*512u + 256u + (unsigned)nsub*16u) = lo.v;
    }
    if (p < QTOT) {    // query entry (unchanged): {x, -g|x|^2, 1, 0}
        float a[8]; float xx = 0.f;
        #pragma unroll
        for (int d = 0; d < 5; ++d) { float x = rss[p*5+d]; a[d] = x; xx += x*x; }
        a[5] = -g * xx; a[6] = 1.0f; a[7] = 0.0f;
        union { ushort_t u[8]; f32x4 v; } hi, lo;
        #pragma unroll
        for (int k = 0; k < 8; ++k) bsplit(a[k], hi.u[k], lo.u[k]);
        *(f32x4*)(ws + AOFF + (unsigned)p*32u)       = hi.v;
        *(f32x4*)(ws + AOFF + (unsigned)p*32u + 16u) = lo.v;
    }
    if (p < PREPN) {   // loc table: tile T, compact entry c = m*4+quad (m<5)
        const int T = p / 20;
        const int c = p - T * 20;
        const int m = c >> 2, qq = c & 3;
        union { ushort_t u[4]; s16x4 v; } e;
        #pragma unroll
        for (int i = 0; i < 4; ++i) {
            const int n = T*16 + qq*4 + i;
            ushort_t h, l, val;
            if (m == 0)      { bsplit(Loc[n*2+0], h, l); val = h; }
            else if (m == 1) { bsplit(Loc[n*2+0], h, l); val = l; }
            else if (m == 2) { bsplit(Loc[n*2+1], h, l); val = h; }
            else if (m == 3) { bsplit(Loc[n*2+1], h, l); val = l; }
            else             { val = b16(1.0f); }
            e.u[i] = val;
        }
        *(s16x4*)(ws + LTOFF + (unsigned)T*160u + (unsigned)c*8u) = e.v;
    }
    if (p < 16) *(f32x4*)(ws + ZOFF + (unsigned)p*16u) = (f32x4){0.f,0.f,0.f,0.f};
}

// exp + bf16-pack + accumulate-MFMA for one q-tile
static __device__ __forceinline__ f32x4 step2(
    const f32x4 t, const s16x4 lt, f32x4 c)
{
    const float s0 = EXP2F(t[0]);
    const float s1 = EXP2F(t[1]);
    const float s2 = EXP2F(t[2]);
    const float s3 = EXP2F(t[3]);
    union { ushort_t u[4]; s16x4 v; } bs;
    bs.u[0] = b16(s0); bs.u[1] = b16(s1); bs.u[2] = b16(s2); bs.u[3] = b16(s3);
    return MFMA16(lt, bs.v, c);
}

__global__ __launch_bounds__(256, 4) void sknn_main(
    const char* __restrict__ tbl, float* __restrict__ part)
{
    const int tid  = threadIdx.x;
    const int lane = tid & 63;
    const int w    = tid >> 6;
    const int nb   = blockIdx.x & (NB - 1);           // XCD swizzle
    const int qg   = blockIdx.x >> 4;
    const int ns   = nb * 4 + w;                      // phase 0..63
    const int qbase = qg * 64;
    const int j  = lane & 15;
    const int qd = lane >> 4;

    // GEMM1 B-frags = queries, K-pattern [Qh|Ql|Qh|0] (quad1 -> lo half)
    const unsigned qb = (qd == 3) ? (ZOFF + (unsigned)j*16u)
        : (AOFF + (unsigned)(qbase + j)*32u + (qd == 1 ? 16u : 0u));
    const unsigned qs = (qd == 3) ? 0u : 512u;        // 16 queries * 32 B
    const s16x8 bq0 = *(const s16x8*)(tbl + qb);
    const s16x8 bq1 = *(const s16x8*)(tbl + qb + qs);
    const s16x8 bq2 = *(const s16x8*)(tbl + qb + 2u*qs);
    const s16x8 bq3 = *(const s16x8*)(tbl + qb + 3u*qs);

    // GEMM1 A-stream = refs, K-pattern [Rh|Rh|Rl|0] (quad2 -> lo half)
    unsigned aofs = (qd == 3) ? (ZOFF + (unsigned)j*16u)
        : (BOFF + (unsigned)ns*512u + (qd == 2 ? 256u : 0u) + (unsigned)j*16u);
    const unsigned astep = (qd == 3) ? 0u : ASTEP_IT;

    // GEMM2 A-stream = loc weights; lane m=j, k=4*qd+i. m>=5 rows are zero.
    unsigned ltofs = (j < 5) ? (LTOFF + (unsigned)ns*160u + (unsigned)(j*4+qd)*8u)
                             : ZOFF;
    const unsigned ltstep = (j < 5) ? LTSTEP_IT : 0u;

    f32x4 c2[4];
    #pragma unroll
    for (int k = 0; k < 4; ++k) c2[k] = (f32x4){0.f, 0.f, 0.f, 0.f};
    const f32x4 zz = {0.f, 0.f, 0.f, 0.f};

    s16x8 acur = *(const s16x8*)(tbl + aofs);
    s16x4 lcur = *(const s16x4*)(tbl + ltofs);

    int nt = ns;
    while (nt + NS < NTILES) {       // hot loop: unconditional prefetch
        aofs  += astep;
        ltofs += ltstep;
        const s16x8 anx = *(const s16x8*)(tbl + aofs);
        const s16x4 lnx = *(const s16x4*)(tbl + ltofs);

        const f32x4 t0 = __builtin_amdgcn_mfma_f32_16x16x32_bf16(acur, bq0, zz, 0, 0, 0);
        const f32x4 t1 = __builtin_amdgcn_mfma_f32_16x16x32_bf16(acur, bq1, zz, 0, 0, 0);
        const f32x4 t2 = __builtin_amdgcn_mfma_f32_16x16x32_bf16(acur, bq2, zz, 0, 0, 0);
        const f32x4 t3 = __builtin_amdgcn_mfma_f32_16x16x32_bf16(acur, bq3, zz, 0, 0, 0);
        c2[0] = step2(t0, lcur, c2[0]);
        c2[1] = step2(t1, lcur, c2[1]);
        c2[2] = step2(t2, lcur, c2[2]);
        c2[3] = step2(t3, lcur, c2[3]);

        acur = anx; lcur = lnx;
        nt += NS;
    }
    {   // final tile
        const f32x4 t0 = __builtin_amdgcn_mfma_f32_16x16x32_bf16(acur, bq0, zz, 0, 0, 0);
        const f32x4 t1 = __builtin_amdgcn_mfma_f32_16x16x32_bf16(acur, bq1, zz, 0, 0, 0);
        const f32x4 t2 = __builtin_amdgcn_mfma_f32_16x16x32_bf16(acur, bq2, zz, 0, 0, 0);
        const f32x4 t3 = __builtin_amdgcn_mfma_f32_16x16x32_bf16(acur, bq3, zz, 0, 0, 0);
        c2[0] = step2(t0, lcur, c2[0]);
        c2[1] = step2(t1, lcur, c2[1]);
        c2[2] = step2(t2, lcur, c2[2]);
        c2[3] = step2(t3, lcur, c2[3]);
    }

    // C2 rows (m = 4*qd + reg): qd0 -> {o0h,o0l,o1h,o1l}; qd1 reg0 -> sum.
    // Fully reduced over this wave's n-subset — no butterfly needed.
    __shared__ float red[4][3][64];
    if (qd == 0) {
        #pragma unroll
        for (int qt = 0; qt < 4; ++qt) {
            red[w][1][qt*16 + j] = c2[qt][0] + c2[qt][1];
            red[w][2][qt*16 + j] = c2[qt][2] + c2[qt][3];
        }
    } else if (qd == 1) {
        #pragma unroll
        for (int qt = 0; qt < 4; ++qt) {
            red[w][0][qt*16 + j] = c2[qt][0];
        }
    }
    __syncthreads();

    if (tid < 192) {   // sum 4 waves, coalesced store (no atomics)
        const int comp = tid >> 6, ql = tid & 63;
        const float v = red[0][comp][ql] + red[1][comp][ql]
                      + red[2][comp][ql] + red[3][comp][ql];
        part[((nb * 3 + comp) << 12) + qbase + ql] = v;
    }
}

__global__ __launch_bounds__(256) void sknn_fin(
    const float* __restrict__ part, float* __restrict__ out)
{
    const int q = blockIdx.x * 256 + threadIdx.x;
    float s = 0.f, w0 = 0.f, w1 = 0.f;
    #pragma unroll
    for (int nb = 0; nb < NB; ++nb) {
        s  += part[((nb * 3 + 0) << 12) + q];
        w0 += part[((nb * 3 + 1) << 12) + q];
        w1 += part[((nb * 3 + 2) << 12) + q];
    }
    const float inv = 1.0f / s;
    out[q * 2 + 0] = w0 * inv;
    out[q * 2 + 1] = w1 * inv;
}

extern "C" void kernel_launch(void* const* d_in, const int* in_sizes, int n_in,
                              void* d_out, int out_size, void* d_ws, size_t ws_size,
                              hipStream_t stream) {
    const float* rss   = (const float*)d_in[0];
    const float* Radio = (const float*)d_in[1];
    const float* Loc   = (const float*)d_in[2];
    const float* sigma = (const float*)d_in[3];
    float* out  = (float*)d_out;
    char*  ws   = (char*)d_ws;
    float* part = (float*)(ws + PARTOFF);

    sknn_prep<<<(PREPN + 255) / 256, dim3(256), 0, stream>>>(rss, Radio, Loc, sigma, ws);
    sknn_main<<<MAINBLOCKS, dim3(256), 0, stream>>>(ws, part);
    sknn_fin<<<QTOT / 256, dim3(256), 0, stream>>>(part, out);
}

// Round 15
// 95.820 us; speedup vs baseline: 1.0344x; 1.0093x over previous
//
#include <hip/hip_runtime.h>
#include <hip/hip_bf16.h>
#include <math.h>

// Q=4096, N=50000, D=5, L=2
// GEMM1 (16x16x32, split-bf16 K-packing, A=refs, B=queries):
//   t[ref][q] tile; C/D: col=lane&15=q, row=4*quad+reg=ref
// s = 2^t -> bf16 (round-half-up via +0x8000, packed by v_perm) -> fed
// DIRECTLY as B-frag of GEMM2 (16x16x16, n=lane&15=q, k=4*quad+i=ref).
// GEMM2 A rows: {l0_hi, l0_lo, l1_hi, l1_lo, 1, 0...} (split-bf16 Loc) ->
// C2 rows accumulate {o0h,o0l,o1h,o1l,sum} over the sweep in AGPRs.
#define QTOT   4096
#define NTOT   50000
#define NTILES 3125            // 50000/16 exactly
#define NS     64              // n-phases; wave phase = nb*4 + waveid
#define NB     16
#define QG     64
#define MAINBLOCKS (QG * NB)   // 1024 blocks = 4096 waves
#define ASTEP_IT  (512u * NS)  // ref-table stride per iter
#define LTSTEP_IT (160u * NS)  // loc-table stride per iter
#define PREPN  (NTILES * 20)   // 62500 compact loc-table entries

// ws layout (bytes); total ~3.02 MB
#define BOFF   0u                          // ref table: [tile][hi16x16B][lo16x16B]
#define BSIZE  (3125u * 512u)              // 1,600,000
#define AOFF   (BOFF + BSIZE)              // query table: [q][hi16B][lo16B]
#define ASIZE  (4096u * 32u)               // 131,072
#define ZOFF   (AOFF + ASIZE)              // 256 B zero block
#define LTOFF  (ZOFF + 256u)               // loc table: [tile][20 entries][8B]
#define LTSIZE (3125u * 160u)              // 500,000
#define PARTOFF (LTOFF + LTSIZE)           // part: [NB][3][4096] f32

typedef unsigned short ushort_t;
typedef short  s16x8 __attribute__((ext_vector_type(8)));
typedef short  s16x4 __attribute__((ext_vector_type(4)));
typedef float  f32x4 __attribute__((ext_vector_type(4)));

#if __has_builtin(__builtin_amdgcn_exp2f)
#define EXP2F(x) __builtin_amdgcn_exp2f(x)
#else
#define EXP2F(x) exp2f(x)
#endif

#if __has_builtin(__builtin_amdgcn_mfma_f32_16x16x16_bf16)
#define MFMA16(a,b,c) __builtin_amdgcn_mfma_f32_16x16x16_bf16(a,b,c,0,0,0)
#else
#define MFMA16(a,b,c) __builtin_amdgcn_mfma_f32_16x16x16bf16_1k(a,b,c,0,0,0)
#endif

static __device__ __forceinline__ void bsplit(float f, ushort_t& h, ushort_t& l) {
    __hip_bfloat16 hb = __float2bfloat16(f);
    float hf = __bfloat162float(hb);
    __hip_bfloat16 lb = __float2bfloat16(f - hf);
    h = *reinterpret_cast<ushort_t*>(&hb);
    l = *reinterpret_cast<ushort_t*>(&lb);
}

static __device__ __forceinline__ ushort_t b16(float f) {
    __hip_bfloat16 hb = __float2bfloat16(f);
    return *reinterpret_cast<ushort_t*>(&hb);
}

__global__ __launch_bounds__(256) void sknn_prep(
    const float* __restrict__ rss, const float* __restrict__ Radio,
    const float* __restrict__ Loc, const float* __restrict__ sigma,
    char* __restrict__ ws)
{
    const int p = blockIdx.x * 256 + threadIdx.x;   // grid covers PREPN
    const float sg = sigma[0];
    const float g  = 1.4426950408889634f / (2.0f * sg * sg);
    const float g2 = 2.0f * g;

    if (p < NTOT) {    // ref entry: {2g*r, 1, -g|r|^2, 0} split-bf16
        float b[8]; float rr = 0.f;
        #pragma unroll
        for (int d = 0; d < 5; ++d) { float r = Radio[p*5+d]; b[d] = g2*r; rr += r*r; }
        b[5] = 1.0f; b[6] = -g * rr; b[7] = 0.0f;
        union { ushort_t u[8]; f32x4 v; } hi, lo;
        #pragma unroll
        for (int k = 0; k < 8; ++k) bsplit(b[k], hi.u[k], lo.u[k]);
        const int nt = p >> 4, nsub = p & 15;
        *(f32x4*)(ws + BOFF + (unsigned)nt*512u + (unsigned)nsub*16u)        = hi.v;
        *(f32x4*)(ws + BOFF + (unsigned)nt*512u + 256u + (unsigned)nsub*16u) = lo.v;
    }
    if (p < QTOT) {    // query entry: {x, -g|x|^2, 1, 0} split-bf16
        float a[8]; float xx = 0.f;
        #pragma unroll
        for (int d = 0; d < 5; ++d) { float x = rss[p*5+d]; a[d] = x; xx += x*x; }
        a[5] = -g * xx; a[6] = 1.0f; a[7] = 0.0f;
        union { ushort_t u[8]; f32x4 v; } hi, lo;
        #pragma unroll
        for (int k = 0; k < 8; ++k) bsplit(a[k], hi.u[k], lo.u[k]);
        *(f32x4*)(ws + AOFF + (unsigned)p*32u)       = hi.v;
        *(f32x4*)(ws + AOFF + (unsigned)p*32u + 16u) = lo.v;
    }
    if (p < PREPN) {   // loc table: tile T, compact entry c = m*4+quad (m<5)
        const int T = p / 20;
        const int c = p - T * 20;
        const int m = c >> 2, qq = c & 3;
        union { ushort_t u[4]; s16x4 v; } e;
        #pragma unroll
        for (int i = 0; i < 4; ++i) {
            const int n = T*16 + qq*4 + i;
            ushort_t h, l, val;
            if (m == 0)      { bsplit(Loc[n*2+0], h, l); val = h; }
            else if (m == 1) { bsplit(Loc[n*2+0], h, l); val = l; }
            else if (m == 2) { bsplit(Loc[n*2+1], h, l); val = h; }
            else if (m == 3) { bsplit(Loc[n*2+1], h, l); val = l; }
            else             { val = b16(1.0f); }
            e.u[i] = val;
        }
        *(s16x4*)(ws + LTOFF + (unsigned)T*160u + (unsigned)c*8u) = e.v;
    }
    if (p < 16) *(f32x4*)(ws + ZOFF + (unsigned)p*16u) = (f32x4){0.f,0.f,0.f,0.f};
}

// exp + bf16 round-half-up pack (v_perm: 1 instr packs 2) + accumulate-MFMA
static __device__ __forceinline__ f32x4 step2(
    const f32x4 t, const s16x4 lt, f32x4 c)
{
    union { unsigned u[4]; float f[4]; } s;
    s.f[0] = EXP2F(t[0]);
    s.f[1] = EXP2F(t[1]);
    s.f[2] = EXP2F(t[2]);
    s.f[3] = EXP2F(t[3]);
    // round-half-up to bf16: +0x8000 then take high 16 bits; s>=0 finite.
    const unsigned w0 = __builtin_amdgcn_perm(s.u[1] + 0x8000u, s.u[0] + 0x8000u, 0x07060302u);
    const unsigned w1 = __builtin_amdgcn_perm(s.u[3] + 0x8000u, s.u[2] + 0x8000u, 0x07060302u);
    union { unsigned w[2]; s16x4 v; } bs;
    bs.w[0] = w0; bs.w[1] = w1;
    return MFMA16(lt, bs.v, c);
}

static __device__ __forceinline__ void tile_step(
    const s16x8 a, const s16x4 lt,
    const s16x8 bq0, const s16x8 bq1, const s16x8 bq2, const s16x8 bq3,
    f32x4* c2)
{
    const f32x4 zz = {0.f, 0.f, 0.f, 0.f};
    const f32x4 t0 = __builtin_amdgcn_mfma_f32_16x16x32_bf16(a, bq0, zz, 0, 0, 0);
    const f32x4 t1 = __builtin_amdgcn_mfma_f32_16x16x32_bf16(a, bq1, zz, 0, 0, 0);
    const f32x4 t2 = __builtin_amdgcn_mfma_f32_16x16x32_bf16(a, bq2, zz, 0, 0, 0);
    const f32x4 t3 = __builtin_amdgcn_mfma_f32_16x16x32_bf16(a, bq3, zz, 0, 0, 0);
    c2[0] = step2(t0, lt, c2[0]);
    c2[1] = step2(t1, lt, c2[1]);
    c2[2] = step2(t2, lt, c2[2]);
    c2[3] = step2(t3, lt, c2[3]);
}

__global__ __launch_bounds__(256, 4) void sknn_main(
    const char* __restrict__ tbl, float* __restrict__ part)
{
    const int tid  = threadIdx.x;
    const int lane = tid & 63;
    const int w    = tid >> 6;
    const int nb   = blockIdx.x & (NB - 1);           // XCD swizzle
    const int qg   = blockIdx.x >> 4;
    const int ns   = nb * 4 + w;                      // phase 0..63
    const int qbase = qg * 64;
    const int j  = lane & 15;
    const int qd = lane >> 4;

    // GEMM1 B-frags = queries, K-pattern [Qh|Ql|Qh|0] (quad1 -> lo half)
    const unsigned qb = (qd == 3) ? (ZOFF + (unsigned)j*16u)
        : (AOFF + (unsigned)(qbase + j)*32u + (qd == 1 ? 16u : 0u));
    const unsigned qs = (qd == 3) ? 0u : 512u;        // 16 queries * 32 B
    const s16x8 bq0 = *(const s16x8*)(tbl + qb);
    const s16x8 bq1 = *(const s16x8*)(tbl + qb + qs);
    const s16x8 bq2 = *(const s16x8*)(tbl + qb + 2u*qs);
    const s16x8 bq3 = *(const s16x8*)(tbl + qb + 3u*qs);

    // GEMM1 A-stream = refs, K-pattern [Rh|Rh|Rl|0] (quad2 -> lo half)
    unsigned aofs = (qd == 3) ? (ZOFF + (unsigned)j*16u)
        : (BOFF + (unsigned)ns*512u + (qd == 2 ? 256u : 0u) + (unsigned)j*16u);
    const unsigned astep = (qd == 3) ? 0u : ASTEP_IT;

    // GEMM2 A-stream = loc weights; lane m=j, k=4*qd+i. m>=5 rows are zero.
    unsigned ltofs = (j < 5) ? (LTOFF + (unsigned)ns*160u + (unsigned)(j*4+qd)*8u)
                             : ZOFF;
    const unsigned ltstep = (j < 5) ? LTSTEP_IT : 0u;

    f32x4 c2[4];
    #pragma unroll
    for (int k = 0; k < 4; ++k) c2[k] = (f32x4){0.f, 0.f, 0.f, 0.f};

    // depth-2 software pipeline (every wave has >= 48 iterations)
    s16x8 a0v = *(const s16x8*)(tbl + aofs);
    s16x4 l0v = *(const s16x4*)(tbl + ltofs);
    unsigned aofs1 = aofs + astep, ltofs1 = ltofs + ltstep;
    s16x8 a1v = *(const s16x8*)(tbl + aofs1);
    s16x4 l1v = *(const s16x4*)(tbl + ltofs1);

    int nt = ns;
    while (nt + 2*NS < NTILES) {     // hot loop: prefetch 2 tiles ahead
        aofs1  += astep;
        ltofs1 += ltstep;
        const s16x8 anx = *(const s16x8*)(tbl + aofs1);
        const s16x4 lnx = *(const s16x4*)(tbl + ltofs1);

        tile_step(a0v, l0v, bq0, bq1, bq2, bq3, c2);

        a0v = a1v; l0v = l1v;
        a1v = anx; l1v = lnx;
        nt += NS;
    }
    tile_step(a0v, l0v, bq0, bq1, bq2, bq3, c2);  // 2 peeled tail iters
    tile_step(a1v, l1v, bq0, bq1, bq2, bq3, c2);

    // C2 rows (m = 4*qd + reg): qd0 -> {o0h,o0l,o1h,o1l}; qd1 reg0 -> sum.
    // Fully reduced over this wave's n-subset — no butterfly needed.
    __shared__ float red[4][3][64];
    if (qd == 0) {
        #pragma unroll
        for (int qt = 0; qt < 4; ++qt) {
            red[w][1][qt*16 + j] = c2[qt][0] + c2[qt][1];
            red[w][2][qt*16 + j] = c2[qt][2] + c2[qt][3];
        }
    } else if (qd == 1) {
        #pragma unroll
        for (int qt = 0; qt < 4; ++qt) {
            red[w][0][qt*16 + j] = c2[qt][0];
        }
    }
    __syncthreads();

    if (tid < 192) {   // sum 4 waves, coalesced store (no atomics)
        const int comp = tid >> 6, ql = tid & 63;
        const float v = red[0][comp][ql] + red[1][comp][ql]
                      + red[2][comp][ql] + red[3][comp][ql];
        part[((nb * 3 + comp) << 12) + qbase + ql] = v;
    }
}

__global__ __launch_bounds__(256) void sknn_fin(
    const float* __restrict__ part, float* __restrict__ out)
{
    const int q = blockIdx.x * 256 + threadIdx.x;
    float s = 0.f, w0 = 0.f, w1 = 0.f;
    #pragma unroll
    for (int nb = 0; nb < NB; ++nb) {
        s  += part[((nb * 3 + 0) << 12) + q];
        w0 += part[((nb * 3 + 1) << 12) + q];
        w1 += part[((nb * 3 + 2) << 12) + q];
    }
    const float inv = 1.0f / s;
    out[q * 2 + 0] = w0 * inv;
    out[q * 2 + 1] = w1 * inv;
}

extern "C" void kernel_launch(void* const* d_in, const int* in_sizes, int n_in,
                              void* d_out, int out_size, void* d_ws, size_t ws_size,
                              hipStream_t stream) {
    const float* rss   = (const float*)d_in[0];
    const float* Radio = (const float*)d_in[1];
    const float* Loc   = (const float*)d_in[2];
    const float* sigma = (const float*)d_in[3];
    float* out  = (float*)d_out;
    char*  ws   = (char*)d_ws;
    float* part = (float*)(ws + PARTOFF);

    sknn_prep<<<(PREPN + 255) / 256, dim3(256), 0, stream>>>(rss, Radio, Loc, sigma, ws);
    sknn_main<<<MAINBLOCKS, dim3(256), 0, stream>>>(ws, part);
    sknn_fin<<<QTOT / 256, dim3(256), 0, stream>>>(part, out);
}